// Round 1
// baseline (198.138 us; speedup 1.0000x reference)
//
#include <hip/hip_runtime.h>
#include <hip/hip_bf16.h>

typedef __bf16 bf16x8 __attribute__((ext_vector_type(8)));
typedef float f32x4 __attribute__((ext_vector_type(4)));

#define GLOBAL_AS(p) ((const __attribute__((address_space(1))) void*)(p))
#define LDS_AS(p)    ((__attribute__((address_space(3))) void*)(p))

static __device__ __forceinline__ unsigned short f2bf(float f) {
    union { float f; unsigned u; } v; v.f = f;
    unsigned r = v.u + 0x7FFFu + ((v.u >> 16) & 1u);
    return (unsigned short)(r >> 16);
}

// ---------------------------------------------------------------------------
// Build Acat bf16 [8192][2048]: row m=b*1024+t -> [x[b,t-1] (0 if t==0), x[b,t]]
// ---------------------------------------------------------------------------
__global__ void prep_a(const float* __restrict__ x, unsigned short* __restrict__ A) {
    const int m = blockIdx.x;          // 0..8191
    const int t = m & 1023;
    const int c = threadIdx.x * 4;     // 256 threads * 4 cols

    float4 v0;
    if (t == 0) v0 = make_float4(0.f, 0.f, 0.f, 0.f);
    else        v0 = *reinterpret_cast<const float4*>(x + (size_t)(m - 1) * 1024 + c);
    float4 v1 = *reinterpret_cast<const float4*>(x + (size_t)m * 1024 + c);

    ushort4 b0 = make_ushort4(f2bf(v0.x), f2bf(v0.y), f2bf(v0.z), f2bf(v0.w));
    ushort4 b1 = make_ushort4(f2bf(v1.x), f2bf(v1.y), f2bf(v1.z), f2bf(v1.w));
    *reinterpret_cast<ushort4*>(A + (size_t)m * 2048 + c) = b0;
    *reinterpret_cast<ushort4*>(A + (size_t)m * 2048 + 1024 + c) = b1;
}

// ---------------------------------------------------------------------------
// Transpose kernel f32 [2048][3072] (W,D flattened) -> KT bf16 [3072][2048]
// ---------------------------------------------------------------------------
__global__ void prep_kt(const float* __restrict__ K, unsigned short* __restrict__ KT) {
    __shared__ float tile[64][65];
    const int bi = blockIdx.x;   // kd tile: 32
    const int bj = blockIdx.y;   // u  tile: 48
    const int tx = threadIdx.x & 63;
    const int ty = threadIdx.x >> 6;   // 0..3

#pragma unroll
    for (int i = 0; i < 16; ++i) {
        int r = ty * 16 + i;
        tile[r][tx] = K[(size_t)(bi * 64 + r) * 3072 + bj * 64 + tx];
    }
    __syncthreads();
#pragma unroll
    for (int i = 0; i < 16; ++i) {
        int r = ty * 16 + i;
        KT[(size_t)(bj * 64 + r) * 2048 + bi * 64 + tx] = f2bf(tile[tx][r]);
    }
}

// ---------------------------------------------------------------------------
// GEMM: gates[8192][3072] = Acat[8192][2048] * KT[3072][2048]^T + bias,
// fused activation (tanh for cols<1024, sigmoid otherwise), f32 out.
// 128x128 tile, BK=64, 4 waves (2x2), global_load_lds w/ pre-swizzled source,
// XOR-swizzled ds_read_b128 (conflict-free).
// ---------------------------------------------------------------------------
__global__ __launch_bounds__(256, 2)
void gemm_gates(const unsigned short* __restrict__ A,
                const unsigned short* __restrict__ BT,
                const float* __restrict__ bias,
                float* __restrict__ G) {
    __shared__ __align__(16) unsigned short As[128 * 64];
    __shared__ __align__(16) unsigned short Bs[128 * 64];

    const int tid  = threadIdx.x;
    const int lane = tid & 63;
    const int wid  = tid >> 6;
    const int wr   = wid >> 1, wc = wid & 1;
    const int m0   = blockIdx.y * 128;
    const int n0   = blockIdx.x * 128;

    f32x4 acc[4][4] = {};

    const int sr = lane >> 3;   // row within 8-row group
    const int sc = lane & 7;    // 16B chunk slot this lane writes

    for (int kt = 0; kt < 2048 / 64; ++kt) {
        const int kbase = kt * 64;
#pragma unroll
        for (int i = 0; i < 4; ++i) {
            const int r0 = wid * 32 + i * 8;
            const int r  = r0 + sr;
            const int cc = sc ^ (r & 7);           // inverse-swizzled source chunk
            const unsigned short* srcA = A  + (size_t)(m0 + r) * 2048 + kbase + cc * 8;
            const unsigned short* srcB = BT + (size_t)(n0 + r) * 2048 + kbase + cc * 8;
            __builtin_amdgcn_global_load_lds(GLOBAL_AS(srcA), LDS_AS(As + r0 * 64), 16, 0, 0);
            __builtin_amdgcn_global_load_lds(GLOBAL_AS(srcB), LDS_AS(Bs + r0 * 64), 16, 0, 0);
        }
        __syncthreads();

#pragma unroll
        for (int ks = 0; ks < 2; ++ks) {
            bf16x8 af[4], bg[4];
#pragma unroll
            for (int m = 0; m < 4; ++m) {
                const int row = wr * 64 + m * 16 + (lane & 15);
                const int c   = ks * 4 + (lane >> 4);
                const int p   = c ^ (row & 7);
                af[m] = *reinterpret_cast<const bf16x8*>(As + row * 64 + p * 8);
            }
#pragma unroll
            for (int n = 0; n < 4; ++n) {
                const int row = wc * 64 + n * 16 + (lane & 15);
                const int c   = ks * 4 + (lane >> 4);
                const int p   = c ^ (row & 7);
                bg[n] = *reinterpret_cast<const bf16x8*>(Bs + row * 64 + p * 8);
            }
#pragma unroll
            for (int m = 0; m < 4; ++m)
#pragma unroll
                for (int n = 0; n < 4; ++n)
                    acc[m][n] = __builtin_amdgcn_mfma_f32_16x16x32_bf16(af[m], bg[n], acc[m][n], 0, 0, 0);
        }
        __syncthreads();
    }

    // Epilogue: bias + activation, store f32. Region uniform per block (1024%128==0).
    const int rgn = n0 >> 10;   // 0=z(tanh), 1=f, 2=o
#pragma unroll
    for (int m = 0; m < 4; ++m) {
#pragma unroll
        for (int n = 0; n < 4; ++n) {
            const int col = n0 + wc * 64 + n * 16 + (lane & 15);
            const float bv = bias[col];
#pragma unroll
            for (int v = 0; v < 4; ++v) {
                const int row = m0 + wr * 64 + m * 16 + ((lane >> 4) * 4) + v;
                const float g = acc[m][n][v] + bv;
                float val;
                if (rgn == 0) {
                    float s = 1.0f / (1.0f + __expf(-2.0f * g));
                    val = 2.0f * s - 1.0f;                       // tanh
                } else {
                    val = 1.0f / (1.0f + __expf(-g));            // sigmoid
                }
                G[(size_t)row * 3072 + col] = val;
            }
        }
    }
}

// ---------------------------------------------------------------------------
// Sequential scan: h_t = o_t * (f_t * h_{t-1} + (1-f_t) * z_t)
// 8192 independent (b,u) chains; 128 blocks x 64 threads -> 128 CUs.
// ---------------------------------------------------------------------------
__global__ void scan_kernel(const float* __restrict__ G, float* __restrict__ out) {
    const int blk = blockIdx.x;               // 0..127
    const int b = blk >> 4;
    const int u = ((blk & 15) << 6) + threadIdx.x;
    const float* g = G + (size_t)b * 1024 * 3072 + u;
    float* o = out + (size_t)b * 1024 * 1024 + u;
    float h = 0.f;
#pragma unroll 16
    for (int t = 0; t < 1024; ++t) {
        const float zv = g[(size_t)t * 3072];
        const float fv = g[(size_t)t * 3072 + 1024];
        const float ov = g[(size_t)t * 3072 + 2048];
        h = ov * (fv * h + (1.f - fv) * zv);
        o[(size_t)t * 1024] = h;
    }
}

// ---------------------------------------------------------------------------
extern "C" void kernel_launch(void* const* d_in, const int* in_sizes, int n_in,
                              void* d_out, int out_size, void* d_ws, size_t ws_size,
                              hipStream_t stream) {
    const float* x    = (const float*)d_in[0];   // [8,1024,1024]
    const float* kern = (const float*)d_in[1];   // [2,1024,3072]
    const float* bias = (const float*)d_in[2];   // [3072]
    float* out = (float*)d_out;                  // [8,1024,1024]

    char* ws = (char*)d_ws;
    unsigned short* A  = (unsigned short*)ws;                              // 33,554,432 B
    unsigned short* KT = (unsigned short*)(ws + 33554432);                 // 12,582,912 B
    float* G           = (float*)(ws + 33554432 + 12582912);               // 100,663,296 B

    prep_a<<<dim3(8192), dim3(256), 0, stream>>>(x, A);
    prep_kt<<<dim3(32, 48), dim3(256), 0, stream>>>(kern, KT);
    gemm_gates<<<dim3(24, 64), dim3(256), 0, stream>>>(A, KT, bias, G);
    scan_kernel<<<dim3(128), dim3(64), 0, stream>>>(G, out);
}

// Round 2
// 177.613 us; speedup vs baseline: 1.1156x; 1.1156x over previous
//
#include <hip/hip_runtime.h>
#include <hip/hip_bf16.h>

typedef __bf16 bf16x8 __attribute__((ext_vector_type(8)));
typedef float f32x4 __attribute__((ext_vector_type(4)));

#define GLOBAL_AS(p) ((const __attribute__((address_space(1))) void*)(p))
#define LDS_AS(p)    ((__attribute__((address_space(3))) void*)(p))

static __device__ __forceinline__ unsigned short f2bf(float f) {
    union { float f; unsigned u; } v; v.f = f;
    unsigned r = v.u + 0x7FFFu + ((v.u >> 16) & 1u);
    return (unsigned short)(r >> 16);
}

// ---------------------------------------------------------------------------
// 4KB zero page (bf16 zeros) used as the A-source for t==0 rows' first half.
// ---------------------------------------------------------------------------
__global__ void zero_page(float4* __restrict__ z) {
    z[threadIdx.x * 4 + 0] = make_float4(0.f, 0.f, 0.f, 0.f);
    z[threadIdx.x * 4 + 1] = make_float4(0.f, 0.f, 0.f, 0.f);
    z[threadIdx.x * 4 + 2] = make_float4(0.f, 0.f, 0.f, 0.f);
    z[threadIdx.x * 4 + 3] = make_float4(0.f, 0.f, 0.f, 0.f);
}

// ---------------------------------------------------------------------------
// Convert x f32 [8192][1024] -> xb bf16 [8192][1024]
// ---------------------------------------------------------------------------
__global__ void prep_xb(const float* __restrict__ x, unsigned short* __restrict__ xb) {
    const int m = blockIdx.x;
    const int c = threadIdx.x * 4;
    float4 v = *reinterpret_cast<const float4*>(x + (size_t)m * 1024 + c);
    ushort4 b = make_ushort4(f2bf(v.x), f2bf(v.y), f2bf(v.z), f2bf(v.w));
    *reinterpret_cast<ushort4*>(xb + (size_t)m * 1024 + c) = b;
}

// ---------------------------------------------------------------------------
// Transpose kernel f32 [2048][3072] (W,D flattened) -> KT bf16 [3072][2048]
// ---------------------------------------------------------------------------
__global__ void prep_kt(const float* __restrict__ K, unsigned short* __restrict__ KT) {
    __shared__ float tile[64][65];
    const int bi = blockIdx.x;   // kd tile: 32
    const int bj = blockIdx.y;   // u  tile: 48
    const int tx = threadIdx.x & 63;
    const int ty = threadIdx.x >> 6;   // 0..3

#pragma unroll
    for (int i = 0; i < 16; ++i) {
        int r = ty * 16 + i;
        tile[r][tx] = K[(size_t)(bi * 64 + r) * 3072 + bj * 64 + tx];
    }
    __syncthreads();
#pragma unroll
    for (int i = 0; i < 16; ++i) {
        int r = ty * 16 + i;
        KT[(size_t)(bj * 64 + r) * 2048 + bi * 64 + tx] = f2bf(tile[tx][r]);
    }
}

// ---------------------------------------------------------------------------
// GEMM: gates[8192][3072] = Acat[8192][2048] * KT[3072][2048]^T + bias,
// where Acat[m] = [x[m-1] (or 0 if t==0), x[m]] is formed implicitly by the
// staging addresses (global_load_lds per-lane source). Fused bias+activation.
// 128x128 tile, BK=64, 4 waves, XOR-swizzled LDS (0 bank conflicts measured).
// ---------------------------------------------------------------------------
__global__ __launch_bounds__(256, 2)
void gemm_gates(const unsigned short* __restrict__ xb,
                const unsigned short* __restrict__ BT,
                const unsigned short* __restrict__ zpage,
                const float* __restrict__ bias,
                float* __restrict__ G) {
    __shared__ __align__(16) unsigned short As[128 * 64];
    __shared__ __align__(16) unsigned short Bs[128 * 64];

    const int tid  = threadIdx.x;
    const int lane = tid & 63;
    const int wid  = tid >> 6;
    const int wr   = wid >> 1, wc = wid & 1;
    const int m0   = blockIdx.y * 128;
    const int n0   = blockIdx.x * 128;

    f32x4 acc[4][4] = {};

    const int sr = lane >> 3;   // row within 8-row group
    const int sc = lane & 7;    // 16B chunk slot this lane writes

    // Precompute per-load source bases (swizzled chunk is fixed per i).
    const unsigned short* srcA_lo[4];  // k<1024 half: xb[m-1] or zero page
    const unsigned short* srcA_hi[4];  // k>=1024 half: xb[m]
    const unsigned short* srcB[4];
#pragma unroll
    for (int i = 0; i < 4; ++i) {
        const int r  = wid * 32 + i * 8 + sr;
        const int cc = sc ^ (r & 7);
        const int srow = m0 + r;
        srcA_hi[i] = xb + (size_t)srow * 1024 + cc * 8;
        srcA_lo[i] = ((srow & 1023) == 0) ? (zpage + cc * 8)
                                          : (xb + (size_t)(srow - 1) * 1024 + cc * 8);
        srcB[i]    = BT + (size_t)(n0 + r) * 2048 + cc * 8;
    }

    for (int kt = 0; kt < 32; ++kt) {
        const int kb = kt * 64;
#pragma unroll
        for (int i = 0; i < 4; ++i) {
            const int r0 = wid * 32 + i * 8;
            const unsigned short* sa = (kt < 16) ? (srcA_lo[i] + kb)
                                                 : (srcA_hi[i] + (kb - 1024));
            __builtin_amdgcn_global_load_lds(GLOBAL_AS(sa),          LDS_AS(As + r0 * 64), 16, 0, 0);
            __builtin_amdgcn_global_load_lds(GLOBAL_AS(srcB[i] + kb), LDS_AS(Bs + r0 * 64), 16, 0, 0);
        }
        __syncthreads();

#pragma unroll
        for (int ks = 0; ks < 2; ++ks) {
            bf16x8 af[4], bg[4];
#pragma unroll
            for (int m = 0; m < 4; ++m) {
                const int row = wr * 64 + m * 16 + (lane & 15);
                const int c   = ks * 4 + (lane >> 4);
                const int p   = c ^ (row & 7);
                af[m] = *reinterpret_cast<const bf16x8*>(As + row * 64 + p * 8);
            }
#pragma unroll
            for (int n = 0; n < 4; ++n) {
                const int row = wc * 64 + n * 16 + (lane & 15);
                const int c   = ks * 4 + (lane >> 4);
                const int p   = c ^ (row & 7);
                bg[n] = *reinterpret_cast<const bf16x8*>(Bs + row * 64 + p * 8);
            }
#pragma unroll
            for (int m = 0; m < 4; ++m)
#pragma unroll
                for (int n = 0; n < 4; ++n)
                    acc[m][n] = __builtin_amdgcn_mfma_f32_16x16x32_bf16(af[m], bg[n], acc[m][n], 0, 0, 0);
        }
        __syncthreads();
    }

    // Epilogue: bias + activation, store f32. Region uniform per block.
    const int rgn = n0 >> 10;   // 0=z(tanh), 1=f, 2=o
#pragma unroll
    for (int m = 0; m < 4; ++m) {
#pragma unroll
        for (int n = 0; n < 4; ++n) {
            const int col = n0 + wc * 64 + n * 16 + (lane & 15);
            const float bv = bias[col];
#pragma unroll
            for (int v = 0; v < 4; ++v) {
                const int row = m0 + wr * 64 + m * 16 + ((lane >> 4) * 4) + v;
                const float g = acc[m][n][v] + bv;
                float val;
                if (rgn == 0) {
                    float s = 1.0f / (1.0f + __expf(-2.0f * g));
                    val = 2.0f * s - 1.0f;                       // tanh
                } else {
                    val = 1.0f / (1.0f + __expf(-g));            // sigmoid
                }
                G[(size_t)row * 3072 + col] = val;
            }
        }
    }
}

// ---------------------------------------------------------------------------
// Chunked parallel scan of h_t = o_t*(f_t*h_{t-1} + (1-f_t)*z_t)
//   = a_t*h_{t-1} + b_t,  a = o*f, b = o*(1-f)*z.
// 8 chunks of 128 steps. Pass 1: per-(chain,chunk) compose (A,B).
// Pass 2+3 fused: compose chunk-start h from (A,B) prefixes, then rescan.
// ---------------------------------------------------------------------------
__global__ void scan_pass1(const float* __restrict__ G, float2* __restrict__ AB) {
    const int bid = blockIdx.x;        // 256 blocks
    const int ug  = bid & 3;           // 256-u group
    const int c   = (bid >> 2) & 7;    // chunk
    const int b   = bid >> 5;          // batch
    const int u   = ug * 256 + threadIdx.x;
    const float* g = G + (size_t)(b * 1024 + c * 128) * 3072 + u;
    float A = 1.f, Bv = 0.f;
#pragma unroll 8
    for (int i = 0; i < 128; ++i) {
        const float zv = g[(size_t)i * 3072];
        const float fv = g[(size_t)i * 3072 + 1024];
        const float ov = g[(size_t)i * 3072 + 2048];
        const float a  = ov * fv;
        const float bb = ov * (1.f - fv) * zv;
        A  = a * A;
        Bv = a * Bv + bb;
    }
    AB[(size_t)(b * 8 + c) * 1024 + u] = make_float2(A, Bv);
}

__global__ void scan_pass23(const float* __restrict__ G, const float2* __restrict__ AB,
                            float* __restrict__ out) {
    const int b  = blockIdx.x >> 3;        // 64 blocks x 1024 threads
    const int ug = blockIdx.x & 7;         // 128-u group
    const int c  = threadIdx.x >> 7;       // chunk 0..7 (wave-uniform)
    const int ui = threadIdx.x & 127;
    const int u  = ug * 128 + ui;

    float h = 0.f;
    for (int j = 0; j < c; ++j) {          // wave-uniform trip count
        float2 p = AB[(size_t)(b * 8 + j) * 1024 + u];
        h = p.x * h + p.y;
    }
    const float* g = G + (size_t)(b * 1024 + c * 128) * 3072 + u;
    float* o = out + (size_t)(b * 1024 + c * 128) * 1024 + u;
#pragma unroll 8
    for (int i = 0; i < 128; ++i) {
        const float zv = g[(size_t)i * 3072];
        const float fv = g[(size_t)i * 3072 + 1024];
        const float ov = g[(size_t)i * 3072 + 2048];
        h = ov * (fv * h + (1.f - fv) * zv);
        o[(size_t)i * 1024] = h;
    }
}

// ---------------------------------------------------------------------------
extern "C" void kernel_launch(void* const* d_in, const int* in_sizes, int n_in,
                              void* d_out, int out_size, void* d_ws, size_t ws_size,
                              hipStream_t stream) {
    const float* x    = (const float*)d_in[0];   // [8,1024,1024]
    const float* kern = (const float*)d_in[1];   // [2,1024,3072]
    const float* bias = (const float*)d_in[2];   // [3072]
    float* out = (float*)d_out;                  // [8,1024,1024]

    char* ws = (char*)d_ws;
    unsigned short* xb   = (unsigned short*)ws;                      // 16,777,216 B
    unsigned short* KT   = (unsigned short*)(ws + 16777216);         // 12,582,912 B
    float* G             = (float*)(ws + 29360128);                  // 100,663,296 B
    float2* AB           = (float2*)(ws + 130023424);                //    524,288 B
    unsigned short* zpg  = (unsigned short*)(ws + 130547712);        //      4,096 B

    zero_page<<<1, 64, 0, stream>>>((float4*)zpg);
    prep_xb<<<dim3(8192), dim3(256), 0, stream>>>(x, xb);
    prep_kt<<<dim3(32, 48), dim3(256), 0, stream>>>(kern, KT);
    gemm_gates<<<dim3(24, 64), dim3(256), 0, stream>>>(xb, KT, zpg, bias, G);
    scan_pass1<<<dim3(256), dim3(256), 0, stream>>>(G, AB);
    scan_pass23<<<dim3(64), dim3(1024), 0, stream>>>(G, AB, out);
}